// Round 1
// 548.948 us; speedup vs baseline: 1.1477x; 1.1477x over previous
//
#include <hip/hip_runtime.h>
#include <hip/hip_bf16.h>

using bf16 = __hip_bfloat16;
typedef __attribute__((ext_vector_type(8))) short short8;
typedef __attribute__((ext_vector_type(4))) float floatx4;

#define NN 50000
#define EE 800000
#define DD 128
#define HH 8
#define CC 16
#define EDD 32
#define DF 512

__device__ __forceinline__ float b2f(bf16 v) { return __bfloat162float(v); }
__device__ __forceinline__ float bs2f(short s) {
    bf16 h = *reinterpret_cast<bf16*>(&s);
    return __bfloat162float(h);
}
__device__ __forceinline__ float bu2f(unsigned short s) {
    unsigned int u = ((unsigned int)s) << 16;
    return *reinterpret_cast<float*>(&u);
}
__device__ __forceinline__ short f2bs(float v) {
    bf16 h = __float2bfloat16(v);
    return *reinterpret_cast<short*>(&h);
}

// ---- edge_index width detection: int64 has zero high-words (values < 50000)
__global__ void k_detect(const int* __restrict__ ei, int* __restrict__ flag)
{
    if (threadIdx.x == 0 && blockIdx.x == 0) {
        int all0 = 1;
        for (int i = 0; i < 16; ++i) all0 &= (ei[2 * i + 1] == 0);
        flag[0] = all0;  // 1 => int64 layout, 0 => int32
    }
}

__device__ __forceinline__ int load_src(const int* ei, int is64, int i)
{
    int s = is64 ? ei[2 * i] : ei[i];
    return (s < 0) ? 0 : (s >= NN ? NN - 1 : s);
}
__device__ __forceinline__ int load_dst(const int* ei, int is64, int i)
{
    int d = is64 ? ei[2 * EE + 2 * i] : ei[EE + i];
    return (d < 0) ? 0 : (d >= NN ? NN - 1 : d);
}

// ---- pack ALL fp32 weights [K][N] into per-lane MFMA B-frag layout (bf16) ----
// frag (ntile,kstep): 64 lanes x 8 bf16, lane=(quad,m): B[k=kstep*32+quad*8+j][n=ntile*16+m]
__global__ void k_packall(const float* __restrict__ Wq, const float* __restrict__ Wk,
                          const float* __restrict__ Wv, const float* __restrict__ Wsk,
                          const float* __restrict__ W1, const float* __restrict__ W2,
                          const float* __restrict__ We,
                          bf16* __restrict__ wqp, bf16* __restrict__ wkp,
                          bf16* __restrict__ wvp, bf16* __restrict__ wskp,
                          bf16* __restrict__ w1p, bf16* __restrict__ w2p,
                          bf16* __restrict__ wep)
{
    int idx = blockIdx.x * 256 + threadIdx.x;
    const float* W; bf16* out; int ksteps, N, local;
    if (idx < 65536) {
        int wsel = idx >> 14; local = idx & 16383;
        W   = (wsel == 0) ? Wq  : (wsel == 1) ? Wk  : (wsel == 2) ? Wv  : Wsk;
        out = (wsel == 0) ? wqp : (wsel == 1) ? wkp : (wsel == 2) ? wvp : wskp;
        ksteps = 4; N = 128;
    } else if (idx < 131072) { local = idx - 65536;  W = W1; out = w1p; ksteps = 4;  N = 512; }
    else if (idx < 196608)   { local = idx - 131072; W = W2; out = w2p; ksteps = 16; N = 128; }
    else if (idx < 200704)   { local = idx - 196608; W = We; out = wep; ksteps = 1;  N = 128; }
    else return;
    int j = local & 7, lane = (local >> 3) & 63, rest = local >> 9;
    int kstep = rest % ksteps, ntile = rest / ksteps;
    int quad = lane >> 4, m = lane & 15;
    int k = kstep * 32 + quad * 8 + j;
    int n = ntile * 16 + m;
    out[local] = __float2bfloat16(W[(size_t)k * N + n]);
}

// ---------------- projections via MFMA: q, k|v packed, skip ----------------
__global__ __launch_bounds__(256) void k_proj(
    const float* __restrict__ x,
    const bf16* __restrict__ wqp, const bf16* __restrict__ wkp,
    const bf16* __restrict__ wvp, const bf16* __restrict__ wskp,
    const float* __restrict__ bq, const float* __restrict__ bk,
    const float* __restrict__ bv, const float* __restrict__ bsk,
    bf16* __restrict__ qb, unsigned int* __restrict__ kvb,
    bf16* __restrict__ skipb)
{
    __shared__ __align__(16) short xs[32][136];
    __shared__ __align__(16) short os[32][520];
    const int t = threadIdx.x;
    const int wave = t >> 6, lane = t & 63;
    const int quad = lane >> 4, m = lane & 15;
    const int n0 = blockIdx.x * 32;

    for (int idx = t; idx < 32 * 32; idx += 256) {
        int row = idx >> 5, g = idx & 31;
        int node = n0 + row;
        float4 xv = {0.f, 0.f, 0.f, 0.f};
        if (node < NN) xv = *reinterpret_cast<const float4*>(&x[(size_t)node * 128 + g * 4]);
        short4 s4;
        s4.x = f2bs(xv.x); s4.y = f2bs(xv.y); s4.z = f2bs(xv.z); s4.w = f2bs(xv.w);
        *reinterpret_cast<short4*>(&xs[row][g * 4]) = s4;
    }
    __syncthreads();

    const bf16* Wp = (wave == 0) ? wqp : (wave == 1) ? wkp : (wave == 2) ? wvp : wskp;
    const float* bias = (wave == 0) ? bq : (wave == 1) ? bk : (wave == 2) ? bv : bsk;

    floatx4 acc[2][8];
#pragma unroll
    for (int mt = 0; mt < 2; ++mt)
#pragma unroll
        for (int nt = 0; nt < 8; ++nt) acc[mt][nt] = (floatx4){0.f, 0.f, 0.f, 0.f};

#pragma unroll
    for (int kstep = 0; kstep < 4; ++kstep) {
        short8 af0 = *reinterpret_cast<const short8*>(&xs[m][kstep * 32 + quad * 8]);
        short8 af1 = *reinterpret_cast<const short8*>(&xs[16 + m][kstep * 32 + quad * 8]);
#pragma unroll
        for (int nt = 0; nt < 8; ++nt) {
            short8 bf = *reinterpret_cast<const short8*>(
                reinterpret_cast<const short*>(Wp) + ((nt * 4 + kstep) * 64 + lane) * 8);
            acc[0][nt] = __builtin_amdgcn_mfma_f32_16x16x32_bf16(af0, bf, acc[0][nt], 0, 0, 0);
            acc[1][nt] = __builtin_amdgcn_mfma_f32_16x16x32_bf16(af1, bf, acc[1][nt], 0, 0, 0);
        }
    }
#pragma unroll
    for (int nt = 0; nt < 8; ++nt) {
        float bs = bias[nt * 16 + m];
#pragma unroll
        for (int mt = 0; mt < 2; ++mt)
#pragma unroll
            for (int r = 0; r < 4; ++r)
                os[mt * 16 + quad * 4 + r][wave * 128 + nt * 16 + m] = f2bs(acc[mt][nt][r] + bs);
    }
    __syncthreads();
    // output: q (bf16), skip (bf16), kv packed as uint (k low16 | v high16)
    for (int idx = t; idx < 32 * 64; idx += 256) {
        int row = idx >> 6, c = idx & 63;
        int node = n0 + row;
        if (node >= NN) continue;
        unsigned int qu  = *reinterpret_cast<const unsigned int*>(&os[row][2 * c]);
        unsigned int ku  = *reinterpret_cast<const unsigned int*>(&os[row][128 + 2 * c]);
        unsigned int vu  = *reinterpret_cast<const unsigned int*>(&os[row][256 + 2 * c]);
        unsigned int sku = *reinterpret_cast<const unsigned int*>(&os[row][384 + 2 * c]);
        reinterpret_cast<unsigned int*>(qb)[(size_t)node * 64 + c] = qu;
        reinterpret_cast<unsigned int*>(skipb)[(size_t)node * 64 + c] = sku;
        uint2 kv;
        kv.x = (ku & 0xffffu) | (vu << 16);          // ch 2c  : k|v
        kv.y = (ku >> 16) | (vu & 0xffff0000u);      // ch 2c+1: k|v
        reinterpret_cast<uint2*>(kvb)[(size_t)node * 64 + c] = kv;
    }
}

// ---------------- CSR build ----------------
__global__ void k_hist(const int* __restrict__ ei, const int* __restrict__ flag,
                       int* __restrict__ deg)
{
    int i = blockIdx.x * 256 + threadIdx.x;
    if (i >= EE) return;
    atomicAdd(&deg[load_dst(ei, flag[0], i)], 1);
}

__global__ __launch_bounds__(1024) void k_scan(const int* __restrict__ deg,
                                               int* __restrict__ rowstart)
{
    __shared__ int s[1024];
    const int t = threadIdx.x;
    const int CH = 49;
    int base = t * CH;
    int sum = 0;
    for (int i = 0; i < CH; i++) {
        int idx = base + i;
        if (idx < NN) sum += deg[idx];
    }
    s[t] = sum;
    __syncthreads();
    int own = sum;
    for (int off = 1; off < 1024; off <<= 1) {
        int v = (t >= off) ? s[t - off] : 0;
        __syncthreads();
        s[t] += v;
        __syncthreads();
    }
    int run = s[t] - own;
    for (int i = 0; i < CH; i++) {
        int idx = base + i;
        if (idx < NN) {
            rowstart[idx] = run;
            run += deg[idx];
        }
    }
    if (t == 0) rowstart[NN] = EE;
}

__global__ void k_scatter(const int* __restrict__ ei, const int* __restrict__ flag,
                          const int* __restrict__ rowstart,
                          int* __restrict__ cursor, int2* __restrict__ srcid)
{
    int i = blockIdx.x * 256 + threadIdx.x;
    if (i >= EE) return;
    int is64 = flag[0];
    int d = load_dst(ei, is64, i);
    int pos = rowstart[d] + atomicAdd(&cursor[d], 1);
    srcid[pos] = make_int2(load_src(ei, is64, i), i);
}

// -------- fused attention: ONE WAVE PER NODE, barrier-free main loop --------
// block = 256 threads = 4 waves = 4 independent dst nodes.
// lane owns channels 2*lane, 2*lane+1 (head = lane>>3, 8 lanes per head).
__global__ __launch_bounds__(256) void k_attn(
    const float* __restrict__ x, const float* __restrict__ edge_attr,
    const bf16* __restrict__ wep,
    const bf16* __restrict__ qb, const unsigned int* __restrict__ kvb,
    const bf16* __restrict__ skipb,
    const int* __restrict__ rowstart, const int2* __restrict__ srcid,
    const float* __restrict__ ln1g, const float* __restrict__ ln1b,
    bf16* __restrict__ hb)
{
    __shared__ __align__(16) short es[4][16][136];  // per-wave e tile [edge][chan]
    __shared__ __align__(16) short wes[4096];        // We B-frags, shared by block
    const int t = threadIdx.x;
    const int wave = t >> 6, lane = t & 63;
    const int quad = lane >> 4, m = lane & 15;
    const int n = blockIdx.x * 4 + wave;   // grid is exactly NN/4 blocks

    // stage We fragments once (8 ntiles x 64 lanes x 8 bf16 = 8KB)
    for (int idx = t; idx < 512; idx += 256)
        *reinterpret_cast<short8*>(&wes[idx * 8]) =
            *reinterpret_cast<const short8*>(reinterpret_cast<const short*>(wep) + idx * 8);
    __syncthreads();   // only barrier in the kernel

    short (*esw)[136] = es[wave];

    unsigned int qp = reinterpret_cast<const unsigned int*>(qb)[(size_t)n * 64 + lane];
    float q0 = bu2f((unsigned short)(qp & 0xffffu));
    float q1 = bu2f((unsigned short)(qp >> 16));

    const int eoff = rowstart[n], eend = rowstart[n + 1];
    float lsum = 0.f, acc0 = 0.f, acc1 = 0.f;

    for (int p0 = eoff; p0 < eend; p0 += 16) {
        int pos = p0 + m;
        int pc = (pos < eend) ? pos : eoff;
        int2 se = srcid[pc];   // lane j (j<16) holds {src,eid} for tile edge j

        // edge_attr A-frag loads FIRST (so MFMA waits only on these, not on kv)
        const float* arow = edge_attr + (size_t)se.y * 32 + quad * 8;
        float4 a0 = *reinterpret_cast<const float4*>(arow);
        float4 a1 = *reinterpret_cast<const float4*>(arow + 4);

        // kv prefetch: 16 coalesced 8B loads, SGPR row base via readlane
        uint2 kvr[16];
#pragma unroll
        for (int j = 0; j < 16; ++j) {
            int sj = __builtin_amdgcn_readlane(se.x, j);
            kvr[j] = reinterpret_cast<const uint2*>(kvb + (size_t)(unsigned)sj * 128)[lane];
        }

        short8 Af;
        Af[0] = f2bs(a0.x); Af[1] = f2bs(a0.y); Af[2] = f2bs(a0.z); Af[3] = f2bs(a0.w);
        Af[4] = f2bs(a1.x); Af[5] = f2bs(a1.y); Af[6] = f2bs(a1.z); Af[7] = f2bs(a1.w);
#pragma unroll
        for (int nt = 0; nt < 8; ++nt) {
            short8 Bf = *reinterpret_cast<const short8*>(&wes[(nt * 64 + lane) * 8]);
            floatx4 C = {0.f, 0.f, 0.f, 0.f};
            C = __builtin_amdgcn_mfma_f32_16x16x32_bf16(Af, Bf, C, 0, 0, 0);
            int col = nt * 16 + m;
#pragma unroll
            for (int r = 0; r < 4; ++r)
                esw[quad * 4 + r][col] = f2bs(C[r]);   // row=edge-in-tile, col=chan
        }
        __builtin_amdgcn_wave_barrier();   // wave-local LDS: order writes before reads

        int cnt = eend - p0; if (cnt > 16) cnt = 16;
#pragma unroll
        for (int j = 0; j < 16; ++j) {
            unsigned int eu = *reinterpret_cast<const unsigned int*>(&esw[j][2 * lane]);
            float e0 = bu2f((unsigned short)(eu & 0xffffu));
            float e1 = bu2f((unsigned short)(eu >> 16));
            float k0 = bu2f((unsigned short)(kvr[j].x & 0xffffu));
            float v0 = bu2f((unsigned short)(kvr[j].x >> 16));
            float k1 = bu2f((unsigned short)(kvr[j].y & 0xffffu));
            float v1 = bu2f((unsigned short)(kvr[j].y >> 16));
            float pr = fmaf(k1 + e1, q1, (k0 + e0) * q0);
            pr += __shfl_xor(pr, 1);
            pr += __shfl_xor(pr, 2);
            pr += __shfl_xor(pr, 4);   // per-head dot over 8 lanes x 2 ch
            float w = (j < cnt) ? __expf(pr * 0.25f) : 0.f;  // 1/sqrt(16); alpha bounded
            lsum += w;
            acc0 = fmaf(v0 + e0, w, acc0);
            acc1 = fmaf(v1 + e1, w, acc1);
        }
        __builtin_amdgcn_wave_barrier();   // order reads before next tile's writes
    }

    float rden = 1.f / (lsum + 1e-16f);
    float attn0 = acc0 * rden, attn1 = acc1 * rden;
    float2 xv = *reinterpret_cast<const float2*>(x + (size_t)n * 128 + 2 * lane);
    unsigned int skp = reinterpret_cast<const unsigned int*>(skipb)[(size_t)n * 64 + lane];
    float pre0 = xv.x + attn0 + bu2f((unsigned short)(skp & 0xffffu));
    float pre1 = xv.y + attn1 + bu2f((unsigned short)(skp >> 16));
    float s1 = pre0 + pre1, s2 = pre0 * pre0 + pre1 * pre1;
#pragma unroll
    for (int off = 1; off < 64; off <<= 1) {
        s1 += __shfl_xor(s1, off);
        s2 += __shfl_xor(s2, off);
    }
    float mu = s1 * (1.f / 128.f);
    float var = s2 * (1.f / 128.f) - mu * mu;
    float inv = rsqrtf(var + 1e-5f);
    float2 g  = *reinterpret_cast<const float2*>(ln1g + 2 * lane);
    float2 bb = *reinterpret_cast<const float2*>(ln1b + 2 * lane);
    float h0 = (pre0 - mu) * inv * g.x + bb.x;
    float h1 = (pre1 - mu) * inv * g.y + bb.y;
    unsigned int hu = (unsigned int)(unsigned short)f2bs(h0) |
                      ((unsigned int)(unsigned short)f2bs(h1) << 16);
    reinterpret_cast<unsigned int*>(hb)[(size_t)n * 64 + lane] = hu;
}

// ---------------- FFN via MFMA + LN2 ----------------
__global__ __launch_bounds__(256) void k_ffn(
    const bf16* __restrict__ hb,
    const bf16* __restrict__ w1p, const float* __restrict__ b1,
    const bf16* __restrict__ w2p, const float* __restrict__ b2,
    const float* __restrict__ ln2g, const float* __restrict__ ln2b,
    float* __restrict__ out)
{
    __shared__ __align__(16) short hs[32][136];
    __shared__ __align__(16) short t1s[32][520];
    float* fs = reinterpret_cast<float*>(&t1s[0][0]);  // [32][132] after t1s is dead
    const int t = threadIdx.x;
    const int wave = t >> 6, lane = t & 63;
    const int quad = lane >> 4, m = lane & 15;
    const int n0 = blockIdx.x * 32;

    for (int idx = t; idx < 32 * 16; idx += 256) {
        int row = idx >> 4, g = idx & 15;
        int node = n0 + row;
        if (node < NN) {
            *reinterpret_cast<float4*>(&hs[row][g * 8]) =
                *reinterpret_cast<const float4*>(&hb[(size_t)node * 128 + g * 8]);
        } else {
            float4 z = {0.f, 0.f, 0.f, 0.f};
            *reinterpret_cast<float4*>(&hs[row][g * 8]) = z;
        }
    }
    __syncthreads();

    floatx4 acc1[2][8];
#pragma unroll
    for (int mt = 0; mt < 2; ++mt)
#pragma unroll
        for (int nt = 0; nt < 8; ++nt) acc1[mt][nt] = (floatx4){0.f, 0.f, 0.f, 0.f};
#pragma unroll
    for (int kstep = 0; kstep < 4; ++kstep) {
        short8 af0 = *reinterpret_cast<const short8*>(&hs[m][kstep * 32 + quad * 8]);
        short8 af1 = *reinterpret_cast<const short8*>(&hs[16 + m][kstep * 32 + quad * 8]);
#pragma unroll
        for (int nt = 0; nt < 8; ++nt) {
            short8 bf = *reinterpret_cast<const short8*>(
                reinterpret_cast<const short*>(w1p) + (((wave * 8 + nt) * 4 + kstep) * 64 + lane) * 8);
            acc1[0][nt] = __builtin_amdgcn_mfma_f32_16x16x32_bf16(af0, bf, acc1[0][nt], 0, 0, 0);
            acc1[1][nt] = __builtin_amdgcn_mfma_f32_16x16x32_bf16(af1, bf, acc1[1][nt], 0, 0, 0);
        }
    }
#pragma unroll
    for (int nt = 0; nt < 8; ++nt) {
        float bs = b1[wave * 128 + nt * 16 + m];
#pragma unroll
        for (int mt = 0; mt < 2; ++mt)
#pragma unroll
            for (int r = 0; r < 4; ++r)
                t1s[mt * 16 + quad * 4 + r][wave * 128 + nt * 16 + m] =
                    f2bs(fmaxf(acc1[mt][nt][r] + bs, 0.f));
    }
    __syncthreads();

    floatx4 acc2[2][2];
#pragma unroll
    for (int mt = 0; mt < 2; ++mt)
#pragma unroll
        for (int nt = 0; nt < 2; ++nt) acc2[mt][nt] = (floatx4){0.f, 0.f, 0.f, 0.f};
#pragma unroll
    for (int kstep = 0; kstep < 16; ++kstep) {
        short8 af0 = *reinterpret_cast<const short8*>(&t1s[m][kstep * 32 + quad * 8]);
        short8 af1 = *reinterpret_cast<const short8*>(&t1s[16 + m][kstep * 32 + quad * 8]);
#pragma unroll
        for (int nt = 0; nt < 2; ++nt) {
            short8 bf = *reinterpret_cast<const short8*>(
                reinterpret_cast<const short*>(w2p) + (((wave * 2 + nt) * 16 + kstep) * 64 + lane) * 8);
            acc2[0][nt] = __builtin_amdgcn_mfma_f32_16x16x32_bf16(af0, bf, acc2[0][nt], 0, 0, 0);
            acc2[1][nt] = __builtin_amdgcn_mfma_f32_16x16x32_bf16(af1, bf, acc2[1][nt], 0, 0, 0);
        }
    }
    __syncthreads();
#pragma unroll
    for (int nt = 0; nt < 2; ++nt) {
        int col = (wave * 2 + nt) * 16 + m;
        float bs = b2[col];
#pragma unroll
        for (int mt = 0; mt < 2; ++mt)
#pragma unroll
            for (int r = 0; r < 4; ++r)
                fs[(mt * 16 + quad * 4 + r) * 132 + col] = acc2[mt][nt][r] + bs;
    }
    __syncthreads();

    for (int rr = 0; rr < 8; ++rr) {
        int row = wave * 8 + rr;
        int node = n0 + row;
        float p0 = bs2f(hs[row][lane]) + fs[row * 132 + lane];
        float p1 = bs2f(hs[row][lane + 64]) + fs[row * 132 + lane + 64];
        float s1 = p0 + p1, s2 = p0 * p0 + p1 * p1;
#pragma unroll
        for (int off = 1; off < 64; off <<= 1) {
            s1 += __shfl_xor(s1, off);
            s2 += __shfl_xor(s2, off);
        }
        float mu = s1 * (1.f / 128.f);
        float var = s2 * (1.f / 128.f) - mu * mu;
        float inv = rsqrtf(var + 1e-5f);
        if (node < NN) {
            out[(size_t)node * 128 + lane] = (p0 - mu) * inv * ln2g[lane] + ln2b[lane];
            out[(size_t)node * 128 + lane + 64] = (p1 - mu) * inv * ln2g[lane + 64] + ln2b[lane + 64];
        }
    }
}

extern "C" void kernel_launch(void* const* d_in, const int* in_sizes, int n_in,
                              void* d_out, int out_size, void* d_ws, size_t ws_size,
                              hipStream_t stream)
{
    const float* x    = (const float*)d_in[0];
    const int*   ei   = (const int*)d_in[1];
    const float* ea   = (const float*)d_in[2];
    const float* Wq   = (const float*)d_in[3];
    const float* bq   = (const float*)d_in[4];
    const float* Wk   = (const float*)d_in[5];
    const float* bk   = (const float*)d_in[6];
    const float* Wv   = (const float*)d_in[7];
    const float* bv   = (const float*)d_in[8];
    const float* We   = (const float*)d_in[9];
    const float* Wsk  = (const float*)d_in[10];
    const float* bsk  = (const float*)d_in[11];
    const float* ln1g = (const float*)d_in[12];
    const float* ln1b = (const float*)d_in[13];
    const float* W1   = (const float*)d_in[14];
    const float* b1   = (const float*)d_in[15];
    const float* W2   = (const float*)d_in[16];
    const float* b2   = (const float*)d_in[17];
    const float* ln2g = (const float*)d_in[18];
    const float* ln2b = (const float*)d_in[19];

    char* ws = (char*)d_ws;
    size_t off = 0;
    auto alloc = [&](size_t bytes) -> void* {
        void* p = ws + off;
        off += (bytes + 255) & ~(size_t)255;
        return p;
    };
    int*   flag     = (int*)alloc(256);
    int*   deg      = (int*)alloc((size_t)NN * 4);
    int*   cursor   = (int*)alloc((size_t)NN * 4);
    int*   rowstart = (int*)alloc((size_t)(NN + 1) * 4);
    int2*  srcid    = (int2*)alloc((size_t)EE * 8);
    bf16*  qb       = (bf16*)alloc((size_t)NN * 128 * 2);
    unsigned int* kvb = (unsigned int*)alloc((size_t)NN * 128 * 4);
    bf16*  skipb    = (bf16*)alloc((size_t)NN * 128 * 2);
    bf16*  hb       = (bf16*)alloc((size_t)NN * 128 * 2);
    bf16*  wqp      = (bf16*)alloc((size_t)16384 * 2);
    bf16*  wkp      = (bf16*)alloc((size_t)16384 * 2);
    bf16*  wvp      = (bf16*)alloc((size_t)16384 * 2);
    bf16*  wskp     = (bf16*)alloc((size_t)16384 * 2);
    bf16*  w1p      = (bf16*)alloc((size_t)65536 * 2);
    bf16*  w2p      = (bf16*)alloc((size_t)65536 * 2);
    bf16*  wep      = (bf16*)alloc((size_t)4096 * 2);

    hipMemsetAsync(deg, 0, (size_t)NN * 4, stream);
    hipMemsetAsync(cursor, 0, (size_t)NN * 4, stream);

    k_detect<<<1, 64, 0, stream>>>(ei, flag);
    k_packall<<<(200704 + 255) / 256, 256, 0, stream>>>(
        Wq, Wk, Wv, Wsk, W1, W2, We, wqp, wkp, wvp, wskp, w1p, w2p, wep);
    k_hist<<<(EE + 255) / 256, 256, 0, stream>>>(ei, flag, deg);
    k_proj<<<(NN + 31) / 32, 256, 0, stream>>>(x, wqp, wkp, wvp, wskp,
                                               bq, bk, bv, bsk, qb, kvb, skipb);
    k_scan<<<1, 1024, 0, stream>>>(deg, rowstart);
    k_scatter<<<(EE + 255) / 256, 256, 0, stream>>>(ei, flag, rowstart, cursor, srcid);
    k_attn<<<(NN + 3) / 4, 256, 0, stream>>>(x, ea, wep, qb, kvb, skipb,
                                             rowstart, srcid, ln1g, ln1b, hb);
    k_ffn<<<(NN + 31) / 32, 256, 0, stream>>>(hb, w1p, b1, w2p, b2, ln2g, ln2b, (float*)d_out);
}